// Round 8
// baseline (215.925 us; speedup 1.0000x reference)
//
#include <hip/hip_runtime.h>
#include <hip/hip_bf16.h>

typedef __bf16 bf16_t;
typedef __bf16 bf16x4 __attribute__((ext_vector_type(4)));
typedef __bf16 bf16x8 __attribute__((ext_vector_type(8)));
typedef float f32x4 __attribute__((ext_vector_type(4)));

#define ALPHA 8.3f
#define CPAD 72
#define NCOL 68

// img: [4][64][256][256] f32, depth: [4][1][256][256] f32,
// weight: [64][64][3][3] f32, bias: [1][64] f32, out: [4][64][254][254] f32

// Repack weight -> bf16 A-fragment order [tap(9)][chunk(2)][mblock(4)][lane(64)][j(8)]
__global__ void repack_w(const float* __restrict__ w, bf16_t* __restrict__ w2) {
    int idx = blockIdx.x * 256 + threadIdx.x;  // 0..36863
    if (idx >= 9 * 2 * 4 * 64 * 8) return;
    int j     = idx & 7;
    int lane  = (idx >> 3) & 63;
    int m     = (idx >> 9) & 3;
    int chunk = (idx >> 11) & 1;
    int tap   = idx >> 12;
    int oc = m * 16 + (lane & 15);
    int c  = chunk * 32 + (lane >> 4) * 8 + j;
    int kt = tap / 3, lt = tap % 3;
    w2[idx] = (bf16_t)w[((oc * 64 + c) * 3 + kt) * 3 + lt];
}

// R0-R7 post-mortem: every schedule that stages img->LDS inside the conv kernel
// pays the transpose on the critical path (67us floor; overlap attempts spill
// or lockstep). R8 PIVOT: hoist the transpose into ONE streaming pre-pass
// (img f32 [C][H][W] -> img_t bf16 [H][W][C], channels contiguous), then the
// conv kernel has NO LDS, NO barriers, NO staging: B-fragments are direct
// coalesced bf16x8 global loads, served by L1/L2 (block working set ~35KB,
// img_t L3-resident). Full occupancy, zero phase lockstep.

// prepass: in-register 4x4 transpose, same unit decomposition as R0's stager.
// block = (b, h, wblk64); thread (cg,colg) handles 4ch x 4w.
__global__ void transpose_img(const float* __restrict__ img, bf16_t* __restrict__ imgt) {
    const int blk  = blockIdx.x;
    const int wblk = blk & 3;
    const int h    = (blk >> 2) & 255;
    const int b    = blk >> 10;
    const int tid  = threadIdx.x;
    const int cg   = tid & 15;
    const int colg = tid >> 4;
    const float* src = img + (size_t)(b * 64 + cg * 4) * 65536 + h * 256 + wblk * 64 + colg * 4;
    const f32x4 v0 = *(const f32x4*)src;
    const f32x4 v1 = *(const f32x4*)(src + 65536);
    const f32x4 v2 = *(const f32x4*)(src + 2 * 65536);
    const f32x4 v3 = *(const f32x4*)(src + 3 * 65536);
    bf16_t* dst = imgt + ((size_t)((b * 256 + h) * 256 + wblk * 64 + colg * 4)) * 64 + cg * 4;
#pragma unroll
    for (int i = 0; i < 4; ++i)
        *(bf16x4*)(dst + (size_t)i * 64) =
            (bf16x4){(bf16_t)v0[i], (bf16_t)v1[i], (bf16_t)v2[i], (bf16_t)v3[i]};
}

// conv: R0's proven consumer, B-fragments straight from img_t. No LDS/barriers.
__global__ __launch_bounds__(256, 2) void depthconv_direct(
    const float* __restrict__ depth, const bf16_t* __restrict__ w2,
    const bf16_t* __restrict__ imgt, const float* __restrict__ bias,
    float* __restrict__ out)
{
    const int blk   = blockIdx.x;
    const int ppair = blk >> 4;
    const int r     = blk & 15;            // (b,qt) stream; 16%8==0 -> XCD-stable
    const int b     = r >> 2;
    const int qt    = r & 3;
    const int p0    = ppair * 2;
    const int q0    = (qt == 3) ? 190 : qt * 64;   // q 190/191 dup-written identically

    const float*  dep = depth + (size_t)b * 65536;
    const bf16x8* tb  = (const bf16x8*)(imgt + (size_t)b * 64 * 65536);  // 8 x bf16x8 per pixel

    const int tid  = threadIdx.x;
    const int wv   = tid >> 6;
    const int lane = tid & 63;
    const int pr   = wv >> 1;          // p-row within pair
    const int mh   = wv & 1;           // oc-half (mblocks 2mh, 2mh+1)
    const int n    = lane & 15;
    const int quad = lane >> 4;
    const int prow = p0 + pr;

    float dc[4];
#pragma unroll
    for (int i = 0; i < 4; ++i)
        dc[i] = dep[(size_t)(prow + 1) * 256 + q0 + 16 * i + n + 1];

    const f32x4 Z = (f32x4){0.f, 0.f, 0.f, 0.f};
    f32x4 acc[2][4];
#pragma unroll
    for (int mm = 0; mm < 2; ++mm)
#pragma unroll
        for (int i = 0; i < 4; ++i) acc[mm][i] = Z;

    const bf16x8* wbase = (const bf16x8*)w2 + (size_t)(mh * 2) * 64 + lane;

    for (int kt = 0; kt < 3; ++kt) {
        float dwv[3][4];
#pragma unroll
        for (int lt = 0; lt < 3; ++lt)
#pragma unroll
            for (int i = 0; i < 4; ++i) {
                float d = dep[(size_t)(prow + kt) * 256 + q0 + 16 * i + n + lt];
                dwv[lt][i] = __expf(-ALPHA * fabsf(d - dc[i]));
            }
#pragma unroll
        for (int lt = 0; lt < 3; ++lt) {
            const int tap = kt * 3 + lt;
            const bf16x8* w2p = wbase + (size_t)tap * 512;
            const bf16x8 a00 = w2p[0];           // chunk0, mm0
            const bf16x8 a01 = w2p[64];          // chunk0, mm1
            const bf16x8 a10 = w2p[256];         // chunk1, mm0
            const bf16x8 a11 = w2p[320];         // chunk1, mm1
#pragma unroll
            for (int i = 0; i < 4; ++i) {
                // pixel (prow+kt, q0+16i+n+lt); chunk0 = ch quad*8.., chunk1 = +32
                const bf16x8* p = tb
                    + ((size_t)(prow + kt) * 256 + (q0 + 16 * i + n + lt)) * 8 + quad;
                const bf16x8 bf0 = p[0];
                const bf16x8 bf1 = p[4];
                f32x4 P0 = __builtin_amdgcn_mfma_f32_16x16x32_bf16(a00, bf0, Z, 0, 0, 0);
                f32x4 P1 = __builtin_amdgcn_mfma_f32_16x16x32_bf16(a01, bf0, Z, 0, 0, 0);
                P0 = __builtin_amdgcn_mfma_f32_16x16x32_bf16(a10, bf1, P0, 0, 0, 0);
                P1 = __builtin_amdgcn_mfma_f32_16x16x32_bf16(a11, bf1, P1, 0, 0, 0);
                acc[0][i] += dwv[lt][i] * P0;
                acc[1][i] += dwv[lt][i] * P1;
            }
        }
    }

    // epilogue: D[row=quad*4+r2][col=n]; oc = (mh*2+mm)*16 + quad*4 + r2
#pragma unroll
    for (int mm = 0; mm < 2; ++mm) {
#pragma unroll
        for (int r2 = 0; r2 < 4; ++r2) {
            const int oc = (mh * 2 + mm) * 16 + quad * 4 + r2;
            const float bz = bias[oc];
#pragma unroll
            for (int i = 0; i < 4; ++i)
                out[((size_t)(b * 64 + oc) * 254 + prow) * 254 + q0 + 16 * i + n]
                    = acc[mm][i][r2] + bz;
        }
    }
}

// -------- legacy fallback (R0, 67.6us): used if workspace too small --------
__global__ __launch_bounds__(256, 2) void depthconv_mfma(
    const float* __restrict__ img, const float* __restrict__ depth,
    const bf16_t* __restrict__ w2, const float* __restrict__ bias,
    float* __restrict__ out)
{
    __shared__ bf16_t lds[4 * NCOL * CPAD];

    const int tid = threadIdx.x;
    const int blk   = blockIdx.x;
    const int ppair = blk >> 4;
    const int r     = blk & 15;
    const int b     = r >> 2;
    const int qt    = r & 3;
    const int p0    = ppair * 2;
    const int q0    = (qt == 3) ? 190 : qt * 64;
    const int s0    = (qt == 3) ? 188 : q0;

    const float* imgb = img + (size_t)b * 64 * 65536;
    const float* dep  = depth + (size_t)b * 65536;

#pragma unroll
    for (int k = 0; k < 5; ++k) {
        int u = tid + (k << 8);
        if (u < 1088) {
            int cg   = u & 15;
            int rest = u >> 4;
            int colg = rest % 17;
            int row  = rest / 17;
            const float* src = imgb + (size_t)(cg * 4) * 65536 + (p0 + row) * 256 + s0 + colg * 4;
            f32x4 v0 = *(const f32x4*)src;
            f32x4 v1 = *(const f32x4*)(src + 65536);
            f32x4 v2 = *(const f32x4*)(src + 2 * 65536);
            f32x4 v3 = *(const f32x4*)(src + 3 * 65536);
            bf16_t* dst = lds + (size_t)(row * NCOL + colg * 4) * CPAD + cg * 4;
#pragma unroll
            for (int i = 0; i < 4; ++i)
                *(bf16x4*)(dst + i * CPAD) =
                    (bf16x4){(bf16_t)v0[i], (bf16_t)v1[i], (bf16_t)v2[i], (bf16_t)v3[i]};
        }
    }
    __syncthreads();

    const int wv   = tid >> 6;
    const int lane = tid & 63;
    const int pr   = wv >> 1;
    const int mh   = wv & 1;
    const int n    = lane & 15;
    const int quad = lane >> 4;
    const int prow = p0 + pr;
    const int clb0 = q0 - s0;

    float dc[4];
#pragma unroll
    for (int i = 0; i < 4; ++i)
        dc[i] = dep[(prow + 1) * 256 + q0 + 16 * i + n + 1];

    const f32x4 Z = (f32x4){0.f, 0.f, 0.f, 0.f};
    f32x4 acc[2][4];
#pragma unroll
    for (int mm = 0; mm < 2; ++mm)
#pragma unroll
        for (int i = 0; i < 4; ++i) acc[mm][i] = Z;

    for (int kt = 0; kt < 3; ++kt) {
        float dwv[3][4];
#pragma unroll
        for (int lt = 0; lt < 3; ++lt)
#pragma unroll
            for (int i = 0; i < 4; ++i) {
                float d = dep[(prow + kt) * 256 + q0 + 16 * i + n + lt];
                dwv[lt][i] = __expf(-ALPHA * fabsf(d - dc[i]));
            }
#pragma unroll
        for (int lt = 0; lt < 3; ++lt) {
            const int tap = kt * 3 + lt;
            const bf16x8* w2p = (const bf16x8*)w2 + ((size_t)(tap * 2) * 4 + mh * 2) * 64 + lane;
            bf16x8 a00 = w2p[0];
            bf16x8 a01 = w2p[64];
            bf16x8 a10 = w2p[256];
            bf16x8 a11 = w2p[256 + 64];
#pragma unroll
            for (int i = 0; i < 4; ++i) {
                const bf16_t* lp = lds
                    + (size_t)((pr + kt) * NCOL + clb0 + 16 * i + n + lt) * CPAD + quad * 8;
                const bf16x8 bf0 = *(const bf16x8*)lp;
                const bf16x8 bf1 = *(const bf16x8*)(lp + 32);
                f32x4 P0 = __builtin_amdgcn_mfma_f32_16x16x32_bf16(a00, bf0, Z, 0, 0, 0);
                f32x4 P1 = __builtin_amdgcn_mfma_f32_16x16x32_bf16(a01, bf0, Z, 0, 0, 0);
                P0 = __builtin_amdgcn_mfma_f32_16x16x32_bf16(a10, bf1, P0, 0, 0, 0);
                P1 = __builtin_amdgcn_mfma_f32_16x16x32_bf16(a11, bf1, P1, 0, 0, 0);
                acc[0][i] += dwv[lt][i] * P0;
                acc[1][i] += dwv[lt][i] * P1;
            }
        }
    }

#pragma unroll
    for (int mm = 0; mm < 2; ++mm) {
#pragma unroll
        for (int r2 = 0; r2 < 4; ++r2) {
            int oc = (mh * 2 + mm) * 16 + quad * 4 + r2;
            float bz = bias[oc];
#pragma unroll
            for (int i = 0; i < 4; ++i) {
                int q = q0 + 16 * i + n;
                out[((size_t)(b * 64 + oc) * 254 + prow) * 254 + q] = acc[mm][i][r2] + bz;
            }
        }
    }
}

extern "C" void kernel_launch(void* const* d_in, const int* in_sizes, int n_in,
                              void* d_out, int out_size, void* d_ws, size_t ws_size,
                              hipStream_t stream) {
    const float* img   = (const float*)d_in[0];
    const float* depth = (const float*)d_in[1];
    const float* w     = (const float*)d_in[2];
    const float* bias  = (const float*)d_in[3];
    bf16_t* w2 = (bf16_t*)d_ws;

    repack_w<<<144, 256, 0, stream>>>(w, w2);

    const size_t IMGT_OFF   = 131072;                       // 128 KiB (w2 = 73.7 KiB)
    const size_t IMGT_BYTES = (size_t)4 * 256 * 256 * 64 * 2;  // 33.55 MB
    if (ws_size >= IMGT_OFF + IMGT_BYTES) {
        bf16_t* imgt = (bf16_t*)((char*)d_ws + IMGT_OFF);
        // 4 b x 256 h x 4 wblk = 4096 blocks
        transpose_img<<<4096, 256, 0, stream>>>(img, imgt);
        // 127 p-pairs x 4 b x 4 q-tiles = 2032 blocks, no LDS, no barriers
        depthconv_direct<<<2032, 256, 0, stream>>>(depth, w2, imgt, bias, (float*)d_out);
    } else {
        depthconv_mfma<<<2032, 256, 0, stream>>>(img, depth, w2, bias, (float*)d_out);
    }
}